// Round 2
// baseline (565.304 us; speedup 1.0000x reference)
//
#include <hip/hip_runtime.h>

// RankingLoss on MI355X.
// inputs: out1 [8192,128] f32, out2 [8192,128] f32, anchor1 [512] i32, anchor2 [512] i32
// output: scalar f32 loss.
//
// R2: dist_kernel rewritten for coalesced stores (LDS-transpose epilogue) and
// 4 blocks/CU occupancy (128 nodes x 64 anchors per block). R1 had 21x write
// amplification (WRITE_SIZE 670MB for a 32MB matrix) from scattered scalar
// stores, and only 2 blocks/CU.

#define NN 8192      // nodes
#define DF 128       // feature dim
#define NA 512       // anchors
#define KK 32        // negatives per anchor
#define VPT 32       // values per thread in select (NN / 256)

// ---------------- reductions ----------------

__device__ __forceinline__ float wave_reduce_f(float x) {
#pragma unroll
  for (int off = 32; off > 0; off >>= 1) x += __shfl_down(x, off);
  return x;
}

__device__ __forceinline__ int wave_reduce_i(int x) {
#pragma unroll
  for (int off = 32; off > 0; off >>= 1) x += __shfl_down(x, off);
  return x;
}

// D = L1(out1[anchor1[a]], out2[anchor2[a]]) + MARGIN, block-wide (blockDim=256)
__device__ __forceinline__ float compute_D(const float* __restrict__ out1,
                                           const float* __restrict__ out2,
                                           const int* __restrict__ anchor1,
                                           const int* __restrict__ anchor2,
                                           int a) {
  __shared__ float dred[4];
  const int tid = threadIdx.x;
  float p = 0.f;
  if (tid < DF) {
    const int r1 = anchor1[a];
    const int r2 = anchor2[a];
    p = fabsf(out1[(size_t)r1 * DF + tid] - out2[(size_t)r2 * DF + tid]);
  }
  p = wave_reduce_f(p);
  const int lane = tid & 63, wid = tid >> 6;
  if (lane == 0) dred[wid] = p;
  __syncthreads();
  return dred[0] + dred[1] + dred[2] + dred[3] + 1.0f;  // MARGIN = 1.0
}

// Exact top-32 ranking-loss partial for one row; u[] = per-thread 32 distance
// bit-patterns (any partition of the 8192 values). Accumulates into *out.
__device__ __forceinline__ void select_accum(const unsigned* u, float Dv,
                                             float* __restrict__ out) {
  __shared__ int redi[4];
  __shared__ float redf[4];
  const int tid = threadIdx.x;
  const int lane = tid & 63, wid = tid >> 6;

  // Bitwise binary search for T = 32nd smallest (bit 31 is 0: distances >= 0).
  unsigned P = 0;
  for (int b = 30; b >= 0; --b) {
    const unsigned mid = P | (1u << b);
    int c = 0;
#pragma unroll
    for (int i = 0; i < VPT; ++i) c += (u[i] < mid) ? 1 : 0;
    c = wave_reduce_i(c);
    __syncthreads();  // redi safe to overwrite (readers of prev iter done)
    if (lane == 0) redi[wid] = c;
    __syncthreads();
    const int tot = redi[0] + redi[1] + redi[2] + redi[3];
    if (tot < KK) P = mid;  // uniform across block
  }

  // Sum relu(D - d) over d < T, count them; ties at T handled analytically.
  float s = 0.f;
  int c = 0;
#pragma unroll
  for (int i = 0; i < VPT; ++i) {
    if (u[i] < P) {
      const float t = Dv - __uint_as_float(u[i]);
      s += (t > 0.f) ? t : 0.f;
      c += 1;
    }
  }
  s = wave_reduce_f(s);
  c = wave_reduce_i(c);
  __syncthreads();
  if (lane == 0) {
    redf[wid] = s;
    redi[wid] = c;
  }
  __syncthreads();
  if (tid == 0) {
    float stot = redf[0] + redf[1] + redf[2] + redf[3];
    const int ctot = redi[0] + redi[1] + redi[2] + redi[3];
    float tt = Dv - __uint_as_float(P);
    if (tt < 0.f) tt = 0.f;
    stot += (float)(KK - ctot) * tt;
    atomicAdd(out, stot * (1.0f / (float)(NA * KK)));
  }
}

// ---------------- kernel 1: distance matrix ----------------
// grid: (64 node tiles, 8 anchor tiles, 2 dirs) = 1024 blocks, block 256.
// Tile: 128 nodes x 64 anchors, dims chunked by 32 through LDS, 8x4 reg tile.
// Epilogue: LDS-transpose staging -> fully coalesced dwordx4 row stores.

__global__ __launch_bounds__(256, 4) void dist_kernel(
    const float* __restrict__ out1, const float* __restrict__ out2,
    const int* __restrict__ anchor1, const int* __restrict__ anchor2,
    float* __restrict__ dist) {
  const int tid = threadIdx.x;
  const int nb = blockIdx.x;   // node tile
  const int ab = blockIdx.y;   // anchor tile
  const int dir = blockIdx.z;  // 0: a1 vs out2, 1: a2 vs out1
  const float* nodes = dir ? out1 : out2;
  const float* asrc = dir ? out2 : out1;
  const int* aidx = dir ? anchor2 : anchor1;
  const int n0 = nb * 128;
  const int a0 = ab * 64;

  __shared__ union {
    struct {
      float nds[128][36];  // node rows, 32-dim chunk + pad
      float ads[64][36];   // anchor rows
    } t;
    float stage[32][132];  // epilogue transpose staging (132*4B = 33*16B ok)
  } sm;
  __shared__ int aind[64];

  if (tid < 64) aind[tid] = aidx[a0 + tid];

  float acc[8][4];
#pragma unroll
  for (int i = 0; i < 8; ++i)
#pragma unroll
    for (int j = 0; j < 4; ++j) acc[i][j] = 0.f;

  const int tn = tid & 15;  // node group:   cols tn + 16*i
  const int ta = tid >> 4;  // anchor group: rows ta + 16*j

  for (int cch = 0; cch < 4; ++cch) {
    const int d0 = cch * 32;
    __syncthreads();  // prev chunk's readers done (also covers aind preload)
#pragma unroll
    for (int r = 0; r < 4; ++r) {
      const int f = tid + 256 * r;  // 0..1023 float4 slots (node tile)
      const int row = f >> 3;       // 0..127
      const int c4 = f & 7;         // 0..7
      *(float4*)&sm.t.nds[row][c4 * 4] =
          *(const float4*)(nodes + (size_t)(n0 + row) * DF + d0 + c4 * 4);
    }
#pragma unroll
    for (int r = 0; r < 2; ++r) {
      const int g = tid + 256 * r;  // 0..511 float4 slots (anchor tile)
      const int row = g >> 3;       // 0..63
      const int c4 = g & 7;
      *(float4*)&sm.t.ads[row][c4 * 4] =
          *(const float4*)(asrc + (size_t)aind[row] * DF + d0 + c4 * 4);
    }
    __syncthreads();
#pragma unroll
    for (int d4 = 0; d4 < 8; ++d4) {
      float4 nv[8], av[4];
#pragma unroll
      for (int i = 0; i < 8; ++i)
        nv[i] = *(const float4*)&sm.t.nds[tn + 16 * i][d4 * 4];
#pragma unroll
      for (int j = 0; j < 4; ++j)
        av[j] = *(const float4*)&sm.t.ads[ta + 16 * j][d4 * 4];
#pragma unroll
      for (int i = 0; i < 8; ++i)
#pragma unroll
        for (int j = 0; j < 4; ++j) {
          acc[i][j] += fabsf(nv[i].x - av[j].x);
          acc[i][j] += fabsf(nv[i].y - av[j].y);
          acc[i][j] += fabsf(nv[i].z - av[j].z);
          acc[i][j] += fabsf(nv[i].w - av[j].w);
        }
    }
  }

  // Epilogue: two 32-row halves through LDS, then coalesced dwordx4 stores
  // (per wave: 2 rows x 512B contiguous, line-aligned).
  const size_t rowbase = (size_t)(dir * NA + a0) * NN + n0;
#pragma unroll
  for (int half = 0; half < 2; ++half) {
    __syncthreads();  // tiles / previous stage fully consumed
#pragma unroll
    for (int j = 0; j < 2; ++j) {
      const int jj = half * 2 + j;
#pragma unroll
      for (int i = 0; i < 8; ++i)
        sm.stage[ta + 16 * j][tn + 16 * i] = acc[i][jj];
    }
    __syncthreads();
#pragma unroll
    for (int s = 0; s < 4; ++s) {
      const int f = tid + 256 * s;  // 0..1023 float4 slots
      const int row = f >> 5;       // 0..31
      const int c4 = f & 31;        // 0..31
      const float4 v = *(const float4*)&sm.stage[row][c4 * 4];
      *(float4*)(dist + rowbase + (size_t)(half * 32 + row) * NN + c4 * 4) = v;
    }
  }
}

// ---------------- kernel 2: selection + loss ----------------
// grid: 1024 blocks (one per (dir, anchor)), block 256.

__global__ __launch_bounds__(256) void select_kernel(
    const float* __restrict__ dist, const float* __restrict__ out1,
    const float* __restrict__ out2, const int* __restrict__ anchor1,
    const int* __restrict__ anchor2, float* __restrict__ out) {
  const int tid = threadIdx.x;
  const int row = blockIdx.x;  // 0..1023
  const int a = row & (NA - 1);

  unsigned u[VPT];
  const float4* drow = (const float4*)(dist + (size_t)row * NN);
#pragma unroll
  for (int g = 0; g < 8; ++g) {
    const float4 t = drow[tid + 256 * g];
    u[4 * g + 0] = __float_as_uint(t.x);
    u[4 * g + 1] = __float_as_uint(t.y);
    u[4 * g + 2] = __float_as_uint(t.z);
    u[4 * g + 3] = __float_as_uint(t.w);
  }

  const float Dv = compute_D(out1, out2, anchor1, anchor2, a);
  select_accum(u, Dv, out);
}

// ---------------- fallback: fused (no workspace) ----------------

__global__ __launch_bounds__(256) void fused_kernel(
    const float* __restrict__ out1, const float* __restrict__ out2,
    const int* __restrict__ anchor1, const int* __restrict__ anchor2,
    float* __restrict__ out) {
  const int tid = threadIdx.x;
  const int row = blockIdx.x;  // 0..1023
  const int dir = row >> 9;
  const int a = row & (NA - 1);
  const float* nodes = dir ? out1 : out2;
  const float* asrc = dir ? out2 : out1;
  const int* aidx = dir ? anchor2 : anchor1;

  __shared__ float ars[DF];
  if (tid < DF / 4) {
    const int arow = aidx[a];
    const float4 t = *(const float4*)(asrc + (size_t)arow * DF + tid * 4);
    *(float4*)&ars[tid * 4] = t;
  }
  __syncthreads();

  unsigned u[VPT];
  for (int i = 0; i < VPT; ++i) {
    const int n = tid + 256 * i;
    const float4* nrow = (const float4*)(nodes + (size_t)n * DF);
    float dsum = 0.f;
    for (int d4 = 0; d4 < DF / 4; ++d4) {
      const float4 t = nrow[d4];
      const float4 av = *(const float4*)&ars[d4 * 4];
      dsum += fabsf(t.x - av.x) + fabsf(t.y - av.y) + fabsf(t.z - av.z) +
              fabsf(t.w - av.w);
    }
    u[i] = __float_as_uint(dsum);
  }
  __syncthreads();

  const float Dv = compute_D(out1, out2, anchor1, anchor2, a);
  select_accum(u, Dv, out);
}

// ---------------- launch ----------------

extern "C" void kernel_launch(void* const* d_in, const int* in_sizes, int n_in,
                              void* d_out, int out_size, void* d_ws,
                              size_t ws_size, hipStream_t stream) {
  const float* out1 = (const float*)d_in[0];
  const float* out2 = (const float*)d_in[1];
  const int* anchor1 = (const int*)d_in[2];
  const int* anchor2 = (const int*)d_in[3];
  float* out = (float*)d_out;

  hipMemsetAsync(d_out, 0, sizeof(float), stream);

  const size_t need = (size_t)2 * NA * NN * sizeof(float);  // 32 MB
  if (ws_size >= need) {
    float* dist = (float*)d_ws;
    dim3 g1(NN / 128, NA / 64, 2);
    dist_kernel<<<g1, 256, 0, stream>>>(out1, out2, anchor1, anchor2, dist);
    select_kernel<<<2 * NA, 256, 0, stream>>>(dist, out1, out2, anchor1,
                                              anchor2, out);
  } else {
    fused_kernel<<<2 * NA, 256, 0, stream>>>(out1, out2, anchor1, anchor2, out);
  }
}

// Round 3
// 254.975 us; speedup vs baseline: 2.2171x; 2.2171x over previous
//
#include <hip/hip_runtime.h>

// RankingLoss on MI355X.
// inputs: out1 [8192,128] f32, out2 [8192,128] f32, anchor1 [512] i32, anchor2 [512] i32
// output: scalar f32 loss.
//
// R3: (a) removed __launch_bounds__ min-wave caps -- R1/R2's mystery HBM
// traffic (670MB..1.5GB for a 32MB matrix) was scratch SPILL from VGPR caps
// (R2: 64 VGPRs vs ~95 live). (b) stage stride 132->136 (2-way banks = free).
// (c) select_kernel: one wave per row, VPT=128 in registers, zero barriers
// (was 62 barriers/row).

#define NN 8192      // nodes
#define DF 128       // feature dim
#define NA 512       // anchors
#define KK 32        // negatives per anchor

// ---------------- reductions ----------------

__device__ __forceinline__ float wave_reduce_f(float x) {
#pragma unroll
  for (int off = 32; off > 0; off >>= 1) x += __shfl_down(x, off);
  return x;
}

__device__ __forceinline__ int wave_reduce_i(int x) {
#pragma unroll
  for (int off = 32; off > 0; off >>= 1) x += __shfl_down(x, off);
  return x;
}

// ---------------- kernel 1: distance matrix ----------------
// grid: (64 node tiles, 8 anchor tiles, 2 dirs) = 1024 blocks, block 256.
// Tile: 128 nodes x 64 anchors, dims chunked by 32 through LDS, 8x4 reg tile.
// Epilogue: LDS-transpose staging (stride 136 -> 2-way banks, free) then
// coalesced dwordx4 stores (512B contiguous per wave-instruction).

__global__ __launch_bounds__(256) void dist_kernel(
    const float* __restrict__ out1, const float* __restrict__ out2,
    const int* __restrict__ anchor1, const int* __restrict__ anchor2,
    float* __restrict__ dist) {
  const int tid = threadIdx.x;
  const int nb = blockIdx.x;   // node tile
  const int ab = blockIdx.y;   // anchor tile
  const int dir = blockIdx.z;  // 0: a1 vs out2, 1: a2 vs out1
  const float* nodes = dir ? out1 : out2;
  const float* asrc = dir ? out2 : out1;
  const int* aidx = dir ? anchor2 : anchor1;
  const int n0 = nb * 128;
  const int a0 = ab * 64;

  __shared__ union {
    struct {
      float nds[128][36];  // node rows, 32-dim chunk + pad (2-way banks)
      float ads[64][36];   // anchor rows
    } t;
    float stage[32][136];  // epilogue transpose staging; 136%32==8 -> 2-way
  } sm;
  __shared__ int aind[64];

  if (tid < 64) aind[tid] = aidx[a0 + tid];

  float acc[8][4];
#pragma unroll
  for (int i = 0; i < 8; ++i)
#pragma unroll
    for (int j = 0; j < 4; ++j) acc[i][j] = 0.f;

  const int tn = tid & 15;  // node group:   cols tn + 16*i
  const int ta = tid >> 4;  // anchor group: rows ta + 16*j

  for (int cch = 0; cch < 4; ++cch) {
    const int d0 = cch * 32;
    __syncthreads();  // prev chunk's readers done (also covers aind preload)
#pragma unroll
    for (int r = 0; r < 4; ++r) {
      const int f = tid + 256 * r;  // 0..1023 float4 slots (node tile)
      const int row = f >> 3;       // 0..127
      const int c4 = f & 7;         // 0..7
      *(float4*)&sm.t.nds[row][c4 * 4] =
          *(const float4*)(nodes + (size_t)(n0 + row) * DF + d0 + c4 * 4);
    }
#pragma unroll
    for (int r = 0; r < 2; ++r) {
      const int g = tid + 256 * r;  // 0..511 float4 slots (anchor tile)
      const int row = g >> 3;       // 0..63
      const int c4 = g & 7;
      *(float4*)&sm.t.ads[row][c4 * 4] =
          *(const float4*)(asrc + (size_t)aind[row] * DF + d0 + c4 * 4);
    }
    __syncthreads();
#pragma unroll
    for (int d4 = 0; d4 < 8; ++d4) {
      float4 nv[8], av[4];
#pragma unroll
      for (int i = 0; i < 8; ++i)
        nv[i] = *(const float4*)&sm.t.nds[tn + 16 * i][d4 * 4];
#pragma unroll
      for (int j = 0; j < 4; ++j)
        av[j] = *(const float4*)&sm.t.ads[ta + 16 * j][d4 * 4];
#pragma unroll
      for (int i = 0; i < 8; ++i)
#pragma unroll
        for (int j = 0; j < 4; ++j) {
          acc[i][j] += fabsf(nv[i].x - av[j].x);
          acc[i][j] += fabsf(nv[i].y - av[j].y);
          acc[i][j] += fabsf(nv[i].z - av[j].z);
          acc[i][j] += fabsf(nv[i].w - av[j].w);
        }
    }
  }

  // Epilogue: two 32-row halves through LDS, then coalesced dwordx4 stores
  // (per wave per instr: 2 rows x 512B contiguous, line-aligned).
  const size_t rowbase = (size_t)(dir * NA + a0) * NN + n0;
#pragma unroll
  for (int half = 0; half < 2; ++half) {
    __syncthreads();  // tiles / previous stage fully consumed
#pragma unroll
    for (int j = 0; j < 2; ++j) {
      const int jj = half * 2 + j;
#pragma unroll
      for (int i = 0; i < 8; ++i)
        sm.stage[ta + 16 * j][tn + 16 * i] = acc[i][jj];
    }
    __syncthreads();
#pragma unroll
    for (int s = 0; s < 4; ++s) {
      const int f = tid + 256 * s;  // 0..1023 float4 slots
      const int row = f >> 5;       // 0..31
      const int c4 = f & 31;        // 0..31
      const float4 v = *(const float4*)&sm.stage[row][c4 * 4];
      *(float4*)(dist + rowbase + (size_t)(half * 32 + row) * NN + c4 * 4) = v;
    }
  }
}

// ---------------- kernel 2: selection + loss (one wave per row) ----------------
// grid: 1024 blocks x 64 threads. Whole row (8192 distances) lives in VGPRs
// (128/lane); bitwise binary search for the exact 32nd-smallest; no barriers.

__global__ __launch_bounds__(64) void select_kernel(
    const float* __restrict__ dist, const float* __restrict__ out1,
    const float* __restrict__ out2, const int* __restrict__ anchor1,
    const int* __restrict__ anchor2, float* __restrict__ out) {
  const int lane = threadIdx.x;
  const int row = blockIdx.x;  // 0..1023
  const int a = row & (NA - 1);

  unsigned u[128];
  const float4* drow = (const float4*)(dist + (size_t)row * NN);
#pragma unroll
  for (int g = 0; g < 32; ++g) {
    const float4 t = drow[lane + 64 * g];
    u[4 * g + 0] = __float_as_uint(t.x);
    u[4 * g + 1] = __float_as_uint(t.y);
    u[4 * g + 2] = __float_as_uint(t.z);
    u[4 * g + 3] = __float_as_uint(t.w);
  }

  // D = L1(out1[anchor1[a]], out2[anchor2[a]]) + margin; 2 dims per lane.
  const int r1 = anchor1[a];
  const int r2 = anchor2[a];
  float p = fabsf(out1[(size_t)r1 * DF + lane] - out2[(size_t)r2 * DF + lane]) +
            fabsf(out1[(size_t)r1 * DF + 64 + lane] -
                  out2[(size_t)r2 * DF + 64 + lane]);
  p = wave_reduce_f(p);
  const float Dv = __shfl(p, 0) + 1.0f;  // MARGIN

  // Bitwise binary search for T = 32nd smallest (bit 31 is 0: dists >= 0).
  unsigned P = 0;
  for (int b = 30; b >= 0; --b) {
    const unsigned mid = P | (1u << b);
    int c = 0;
#pragma unroll
    for (int i = 0; i < 128; ++i) c += (u[i] < mid) ? 1 : 0;
    c = wave_reduce_i(c);
    if (__shfl(c, 0) < KK) P = mid;  // uniform across wave
  }

  // Sum relu(D - d) over d < T, count; ties at T handled analytically.
  float s = 0.f;
  int c = 0;
#pragma unroll
  for (int i = 0; i < 128; ++i) {
    if (u[i] < P) {
      const float t = Dv - __uint_as_float(u[i]);
      s += (t > 0.f) ? t : 0.f;
      c += 1;
    }
  }
  s = wave_reduce_f(s);
  c = wave_reduce_i(c);
  if (lane == 0) {
    float tt = Dv - __uint_as_float(P);
    if (tt < 0.f) tt = 0.f;
    const float stot = s + (float)(KK - c) * tt;
    atomicAdd(out, stot * (1.0f / (float)(NA * KK)));
  }
}

// ---------------- fallback: fused (no workspace), block-wide ----------------

__device__ __forceinline__ float compute_D_block(
    const float* __restrict__ out1, const float* __restrict__ out2,
    const int* __restrict__ anchor1, const int* __restrict__ anchor2, int a) {
  __shared__ float dred[4];
  const int tid = threadIdx.x;
  float p = 0.f;
  if (tid < DF) {
    const int r1 = anchor1[a];
    const int r2 = anchor2[a];
    p = fabsf(out1[(size_t)r1 * DF + tid] - out2[(size_t)r2 * DF + tid]);
  }
  p = wave_reduce_f(p);
  const int lane = tid & 63, wid = tid >> 6;
  if (lane == 0) dred[wid] = p;
  __syncthreads();
  return dred[0] + dred[1] + dred[2] + dred[3] + 1.0f;
}

__global__ __launch_bounds__(256) void fused_kernel(
    const float* __restrict__ out1, const float* __restrict__ out2,
    const int* __restrict__ anchor1, const int* __restrict__ anchor2,
    float* __restrict__ out) {
  const int tid = threadIdx.x;
  const int row = blockIdx.x;  // 0..1023
  const int dir = row >> 9;
  const int a = row & (NA - 1);
  const float* nodes = dir ? out1 : out2;
  const float* asrc = dir ? out2 : out1;
  const int* aidx = dir ? anchor2 : anchor1;

  __shared__ float ars[DF];
  __shared__ int redi[4];
  __shared__ float redf[4];
  if (tid < DF / 4) {
    const int arow = aidx[a];
    *(float4*)&ars[tid * 4] = *(const float4*)(asrc + (size_t)arow * DF + tid * 4);
  }
  __syncthreads();

  unsigned u[32];
  for (int i = 0; i < 32; ++i) {
    const int n = tid + 256 * i;
    const float4* nrow = (const float4*)(nodes + (size_t)n * DF);
    float dsum = 0.f;
    for (int d4 = 0; d4 < DF / 4; ++d4) {
      const float4 t = nrow[d4];
      const float4 av = *(const float4*)&ars[d4 * 4];
      dsum += fabsf(t.x - av.x) + fabsf(t.y - av.y) + fabsf(t.z - av.z) +
              fabsf(t.w - av.w);
    }
    u[i] = __float_as_uint(dsum);
  }
  __syncthreads();

  const float Dv = compute_D_block(out1, out2, anchor1, anchor2, a);
  const int lane = tid & 63, wid = tid >> 6;

  unsigned P = 0;
  for (int b = 30; b >= 0; --b) {
    const unsigned mid = P | (1u << b);
    int c = 0;
#pragma unroll
    for (int i = 0; i < 32; ++i) c += (u[i] < mid) ? 1 : 0;
    c = wave_reduce_i(c);
    __syncthreads();
    if (lane == 0) redi[wid] = c;
    __syncthreads();
    const int tot = redi[0] + redi[1] + redi[2] + redi[3];
    if (tot < KK) P = mid;
  }

  float s = 0.f;
  int c = 0;
#pragma unroll
  for (int i = 0; i < 32; ++i) {
    if (u[i] < P) {
      const float t = Dv - __uint_as_float(u[i]);
      s += (t > 0.f) ? t : 0.f;
      c += 1;
    }
  }
  s = wave_reduce_f(s);
  c = wave_reduce_i(c);
  __syncthreads();
  if (lane == 0) {
    redf[wid] = s;
    redi[wid] = c;
  }
  __syncthreads();
  if (tid == 0) {
    float stot = redf[0] + redf[1] + redf[2] + redf[3];
    const int ctot = redi[0] + redi[1] + redi[2] + redi[3];
    float tt = Dv - __uint_as_float(P);
    if (tt < 0.f) tt = 0.f;
    stot += (float)(KK - ctot) * tt;
    atomicAdd(out, stot * (1.0f / (float)(NA * KK)));
  }
}

// ---------------- launch ----------------

extern "C" void kernel_launch(void* const* d_in, const int* in_sizes, int n_in,
                              void* d_out, int out_size, void* d_ws,
                              size_t ws_size, hipStream_t stream) {
  const float* out1 = (const float*)d_in[0];
  const float* out2 = (const float*)d_in[1];
  const int* anchor1 = (const int*)d_in[2];
  const int* anchor2 = (const int*)d_in[3];
  float* out = (float*)d_out;

  hipMemsetAsync(d_out, 0, sizeof(float), stream);

  const size_t need = (size_t)2 * NA * NN * sizeof(float);  // 32 MB
  if (ws_size >= need) {
    float* dist = (float*)d_ws;
    dim3 g1(NN / 128, NA / 64, 2);
    dist_kernel<<<g1, 256, 0, stream>>>(out1, out2, anchor1, anchor2, dist);
    select_kernel<<<2 * NA, 64, 0, stream>>>(dist, out1, out2, anchor1,
                                             anchor2, out);
  } else {
    fused_kernel<<<2 * NA, 256, 0, stream>>>(out1, out2, anchor1, anchor2, out);
  }
}

// Round 5
// 166.791 us; speedup vs baseline: 3.3893x; 1.5287x over previous
//
#include <hip/hip_runtime.h>

// RankingLoss on MI355X.
// inputs: out1 [8192,128] f32, out2 [8192,128] f32, anchor1 [512] i32, anchor2 [512] i32
// output: scalar f32 loss.
//
// R5 == R4 with the cvt_pkrtz return-type fix (builtin returns __fp16x2, not
// _Float16x2).
// R4: (a) dist core in packed-f16 |a-b| (pk_sub + and-mask) with
// v_dot2_f32_f16 accumulation into f32 -> 1.5 VALU inst/elem (was 2) and
// half the LDS bytes; LDS stride 20 uints keeps b128 reads 16B-aligned and
// <=2-way banked. (b) __launch_bounds__(256,3): VGPR cap 170 (live ~110,
// no spill -- R2 showed hard caps below liveness explode into scratch).
// (c) select: 2 waves/row (8 waves/CU), #pragma unroll 1 on the 31-round
// bit loop (R3's fully-unrolled search ~80KB code -> I$ suspect), D in f32.

#define NN 8192      // nodes
#define DF 128       // feature dim
#define NA 512       // anchors
#define KK 32        // negatives per anchor

typedef _Float16 h2 __attribute__((ext_vector_type(2)));

// ---------------- helpers ----------------

__device__ __forceinline__ float wave_reduce_f(float x) {
#pragma unroll
  for (int off = 32; off > 0; off >>= 1) x += __shfl_down(x, off);
  return x;
}

__device__ __forceinline__ int wave_reduce_i(int x) {
#pragma unroll
  for (int off = 32; off > 0; off >>= 1) x += __shfl_down(x, off);
  return x;
}

// acc += |a-b|.lo + |a-b|.hi  for packed f16 pairs, f32 accumulate.
__device__ __forceinline__ float absdiff_dot2(unsigned a, unsigned b,
                                              float acc) {
  h2 ha = __builtin_bit_cast(h2, a);
  h2 hb = __builtin_bit_cast(h2, b);
  h2 d = ha - hb;                                        // v_pk_add_f16 (neg)
  unsigned m = __builtin_bit_cast(unsigned, d) & 0x7FFF7FFFu;  // packed abs
  h2 ad = __builtin_bit_cast(h2, m);
  const h2 one = {(_Float16)1.0f, (_Float16)1.0f};
  return __builtin_amdgcn_fdot2(ad, one, acc, false);    // v_dot2_f32_f16
}

// float4 (4 dims f32) -> 2 packed f16 pairs
__device__ __forceinline__ uint2 cvt4_f16(float4 v) {
  uint2 r;
  r.x = __builtin_bit_cast(unsigned, __builtin_amdgcn_cvt_pkrtz(v.x, v.y));
  r.y = __builtin_bit_cast(unsigned, __builtin_amdgcn_cvt_pkrtz(v.z, v.w));
  return r;
}

// ---------------- kernel 1: distance matrix ----------------
// grid: (64 node tiles, 8 anchor tiles, 2 dirs) = 1024 blocks, block 256.
// Tile: 128 nodes x 64 anchors; dims chunked by 32 through LDS as packed f16
// (stride 20 uints: 16B-aligned b128 reads, <=2-way banks). 8x4 f32 acc tile.
// Epilogue: f32 LDS-transpose staging then coalesced dwordx4 stores.

__global__ __launch_bounds__(256, 3) void dist_kernel(
    const float* __restrict__ out1, const float* __restrict__ out2,
    const int* __restrict__ anchor1, const int* __restrict__ anchor2,
    float* __restrict__ dist) {
  const int tid = threadIdx.x;
  const int nb = blockIdx.x;   // node tile
  const int ab = blockIdx.y;   // anchor tile
  const int dir = blockIdx.z;  // 0: a1 vs out2, 1: a2 vs out1
  const float* nodes = dir ? out1 : out2;
  const float* asrc = dir ? out2 : out1;
  const int* aidx = dir ? anchor2 : anchor1;
  const int n0 = nb * 128;
  const int a0 = ab * 64;

  __shared__ union {
    struct {
      unsigned nds[128][20];  // node rows: 16 uints = 32 f16 dims + pad
      unsigned ads[64][20];   // anchor rows
    } t;
    float stage[32][136];  // epilogue transpose staging (2-way banks, free)
  } sm;
  __shared__ int aind[64];

  if (tid < 64) aind[tid] = aidx[a0 + tid];

  float acc[8][4];
#pragma unroll
  for (int i = 0; i < 8; ++i)
#pragma unroll
    for (int j = 0; j < 4; ++j) acc[i][j] = 0.f;

  const int tn = tid & 15;  // node group:   cols tn + 16*i
  const int ta = tid >> 4;  // anchor group: rows ta + 16*j

  for (int cch = 0; cch < 4; ++cch) {
    const int d0 = cch * 32;
    __syncthreads();  // prev chunk's readers done (also covers aind preload)
#pragma unroll
    for (int r = 0; r < 4; ++r) {
      const int f = tid + 256 * r;  // 0..1023 float4 slots (node tile)
      const int row = f >> 3;       // 0..127
      const int c4 = f & 7;         // 0..7 (4 dims each)
      const float4 v =
          *(const float4*)(nodes + (size_t)(n0 + row) * DF + d0 + c4 * 4);
      *(uint2*)&sm.t.nds[row][c4 * 2] = cvt4_f16(v);
    }
#pragma unroll
    for (int r = 0; r < 2; ++r) {
      const int g = tid + 256 * r;  // 0..511 float4 slots (anchor tile)
      const int row = g >> 3;       // 0..63
      const int c4 = g & 7;
      const float4 v =
          *(const float4*)(asrc + (size_t)aind[row] * DF + d0 + c4 * 4);
      *(uint2*)&sm.t.ads[row][c4 * 2] = cvt4_f16(v);
    }
    __syncthreads();
#pragma unroll
    for (int d8 = 0; d8 < 4; ++d8) {  // 8 dims (4 uints) per step
      uint4 nv[8], av[4];
#pragma unroll
      for (int i = 0; i < 8; ++i)
        nv[i] = *(const uint4*)&sm.t.nds[tn + 16 * i][d8 * 4];
#pragma unroll
      for (int j = 0; j < 4; ++j)
        av[j] = *(const uint4*)&sm.t.ads[ta + 16 * j][d8 * 4];
#pragma unroll
      for (int i = 0; i < 8; ++i)
#pragma unroll
        for (int j = 0; j < 4; ++j) {
          acc[i][j] = absdiff_dot2(nv[i].x, av[j].x, acc[i][j]);
          acc[i][j] = absdiff_dot2(nv[i].y, av[j].y, acc[i][j]);
          acc[i][j] = absdiff_dot2(nv[i].z, av[j].z, acc[i][j]);
          acc[i][j] = absdiff_dot2(nv[i].w, av[j].w, acc[i][j]);
        }
    }
  }

  // Epilogue: two 32-row halves through LDS, then coalesced dwordx4 stores.
  const size_t rowbase = (size_t)(dir * NA + a0) * NN + n0;
#pragma unroll
  for (int half = 0; half < 2; ++half) {
    __syncthreads();  // tiles / previous stage fully consumed
#pragma unroll
    for (int j = 0; j < 2; ++j) {
      const int jj = half * 2 + j;
#pragma unroll
      for (int i = 0; i < 8; ++i)
        sm.stage[ta + 16 * j][tn + 16 * i] = acc[i][jj];
    }
    __syncthreads();
#pragma unroll
    for (int s = 0; s < 4; ++s) {
      const int f = tid + 256 * s;  // 0..1023 float4 slots
      const int row = f >> 5;       // 0..31
      const int c4 = f & 31;        // 0..31
      const float4 v = *(const float4*)&sm.stage[row][c4 * 4];
      *(float4*)(dist + rowbase + (size_t)(half * 32 + row) * NN + c4 * 4) = v;
    }
  }
}

// ---------------- kernel 2: selection + loss ----------------
// grid: 1024 blocks x 128 threads (2 waves per row, 8 waves/CU).
// Row's 8192 distances live in VGPRs (64/lane); exact 32nd-smallest via
// 31-round bitwise search (outer loop NOT unrolled -> small I-footprint).

__global__ __launch_bounds__(128) void select_kernel(
    const float* __restrict__ dist, const float* __restrict__ out1,
    const float* __restrict__ out2, const int* __restrict__ anchor1,
    const int* __restrict__ anchor2, float* __restrict__ out) {
  const int tid = threadIdx.x;
  const int lane = tid & 63, w = tid >> 6;
  const int row = blockIdx.x;  // 0..1023
  const int a = row & (NA - 1);

  __shared__ float dred[2];
  __shared__ int cred[2];
  __shared__ float fred[2];
  __shared__ int cred2[2];

  unsigned u[64];
  const float4* drow = (const float4*)(dist + (size_t)row * NN);
#pragma unroll
  for (int g = 0; g < 16; ++g) {
    const float4 t = drow[tid + 128 * g];
    u[4 * g + 0] = __float_as_uint(t.x);
    u[4 * g + 1] = __float_as_uint(t.y);
    u[4 * g + 2] = __float_as_uint(t.z);
    u[4 * g + 3] = __float_as_uint(t.w);
  }

  // D = L1(out1[anchor1[a]], out2[anchor2[a]]) + margin, exact f32.
  const int r1 = anchor1[a];
  const int r2 = anchor2[a];
  float p = fabsf(out1[(size_t)r1 * DF + tid] - out2[(size_t)r2 * DF + tid]);
  p = wave_reduce_f(p);
  if (lane == 0) dred[w] = p;
  __syncthreads();
  const float Dv = dred[0] + dred[1] + 1.0f;  // MARGIN

  // Bitwise binary search for T = 32nd smallest (bit 31 is 0: dists >= 0).
  unsigned P = 0;
#pragma unroll 1
  for (int b = 30; b >= 0; --b) {
    const unsigned mid = P | (1u << b);
    int c = 0;
#pragma unroll
    for (int i = 0; i < 64; ++i) c += (u[i] < mid) ? 1 : 0;
    c = wave_reduce_i(c);
    __syncthreads();  // cred readers of prev round done
    if (lane == 0) cred[w] = c;
    __syncthreads();
    if (cred[0] + cred[1] < KK) P = mid;  // uniform across block
  }

  // Sum relu(D - d) over d < T, count; ties at T handled analytically.
  float s = 0.f;
  int c = 0;
#pragma unroll
  for (int i = 0; i < 64; ++i) {
    if (u[i] < P) {
      const float t = Dv - __uint_as_float(u[i]);
      s += (t > 0.f) ? t : 0.f;
      c += 1;
    }
  }
  s = wave_reduce_f(s);
  c = wave_reduce_i(c);
  if (lane == 0) {
    fred[w] = s;
    cred2[w] = c;
  }
  __syncthreads();
  if (tid == 0) {
    float tt = Dv - __uint_as_float(P);
    if (tt < 0.f) tt = 0.f;
    const float stot =
        fred[0] + fred[1] + (float)(KK - (cred2[0] + cred2[1])) * tt;
    atomicAdd(out, stot * (1.0f / (float)(NA * KK)));
  }
}

// ---------------- fallback: fused (no workspace), block-wide ----------------

__device__ __forceinline__ float compute_D_block(
    const float* __restrict__ out1, const float* __restrict__ out2,
    const int* __restrict__ anchor1, const int* __restrict__ anchor2, int a) {
  __shared__ float dred[4];
  const int tid = threadIdx.x;
  float p = 0.f;
  if (tid < DF) {
    const int r1 = anchor1[a];
    const int r2 = anchor2[a];
    p = fabsf(out1[(size_t)r1 * DF + tid] - out2[(size_t)r2 * DF + tid]);
  }
  p = wave_reduce_f(p);
  const int lane = tid & 63, wid = tid >> 6;
  if (lane == 0) dred[wid] = p;
  __syncthreads();
  return dred[0] + dred[1] + dred[2] + dred[3] + 1.0f;
}

__global__ __launch_bounds__(256) void fused_kernel(
    const float* __restrict__ out1, const float* __restrict__ out2,
    const int* __restrict__ anchor1, const int* __restrict__ anchor2,
    float* __restrict__ out) {
  const int tid = threadIdx.x;
  const int row = blockIdx.x;  // 0..1023
  const int dir = row >> 9;
  const int a = row & (NA - 1);
  const float* nodes = dir ? out1 : out2;
  const float* asrc = dir ? out2 : out1;
  const int* aidx = dir ? anchor2 : anchor1;

  __shared__ float ars[DF];
  __shared__ int redi[4];
  __shared__ float redf[4];
  if (tid < DF / 4) {
    const int arow = aidx[a];
    *(float4*)&ars[tid * 4] =
        *(const float4*)(asrc + (size_t)arow * DF + tid * 4);
  }
  __syncthreads();

  unsigned u[32];
  for (int i = 0; i < 32; ++i) {
    const int n = tid + 256 * i;
    const float4* nrow = (const float4*)(nodes + (size_t)n * DF);
    float dsum = 0.f;
    for (int d4 = 0; d4 < DF / 4; ++d4) {
      const float4 t = nrow[d4];
      const float4 av = *(const float4*)&ars[d4 * 4];
      dsum += fabsf(t.x - av.x) + fabsf(t.y - av.y) + fabsf(t.z - av.z) +
              fabsf(t.w - av.w);
    }
    u[i] = __float_as_uint(dsum);
  }
  __syncthreads();

  const float Dv = compute_D_block(out1, out2, anchor1, anchor2, a);
  const int lane = tid & 63, wid = tid >> 6;

  unsigned P = 0;
#pragma unroll 1
  for (int b = 30; b >= 0; --b) {
    const unsigned mid = P | (1u << b);
    int c = 0;
#pragma unroll
    for (int i = 0; i < 32; ++i) c += (u[i] < mid) ? 1 : 0;
    c = wave_reduce_i(c);
    __syncthreads();
    if (lane == 0) redi[wid] = c;
    __syncthreads();
    const int tot = redi[0] + redi[1] + redi[2] + redi[3];
    if (tot < KK) P = mid;
  }

  float s = 0.f;
  int c = 0;
#pragma unroll
  for (int i = 0; i < 32; ++i) {
    if (u[i] < P) {
      const float t = Dv - __uint_as_float(u[i]);
      s += (t > 0.f) ? t : 0.f;
      c += 1;
    }
  }
  s = wave_reduce_f(s);
  c = wave_reduce_i(c);
  __syncthreads();
  if (lane == 0) {
    redf[wid] = s;
    redi[wid] = c;
  }
  __syncthreads();
  if (tid == 0) {
    float stot = redf[0] + redf[1] + redf[2] + redf[3];
    const int ctot = redi[0] + redi[1] + redi[2] + redi[3];
    float tt = Dv - __uint_as_float(P);
    if (tt < 0.f) tt = 0.f;
    stot += (float)(KK - ctot) * tt;
    atomicAdd(out, stot * (1.0f / (float)(NA * KK)));
  }
}

// ---------------- launch ----------------

extern "C" void kernel_launch(void* const* d_in, const int* in_sizes, int n_in,
                              void* d_out, int out_size, void* d_ws,
                              size_t ws_size, hipStream_t stream) {
  const float* out1 = (const float*)d_in[0];
  const float* out2 = (const float*)d_in[1];
  const int* anchor1 = (const int*)d_in[2];
  const int* anchor2 = (const int*)d_in[3];
  float* out = (float*)d_out;

  (void)hipMemsetAsync(d_out, 0, sizeof(float), stream);

  const size_t need = (size_t)2 * NA * NN * sizeof(float);  // 32 MB
  if (ws_size >= need) {
    float* dist = (float*)d_ws;
    dim3 g1(NN / 128, NA / 64, 2);
    dist_kernel<<<g1, 256, 0, stream>>>(out1, out2, anchor1, anchor2, dist);
    select_kernel<<<2 * NA, 128, 0, stream>>>(dist, out1, out2, anchor1,
                                              anchor2, out);
  } else {
    fused_kernel<<<2 * NA, 256, 0, stream>>>(out1, out2, anchor1, anchor2, out);
  }
}